// Round 6
// baseline (538.128 us; speedup 1.0000x reference)
//
#include <hip/hip_runtime.h>
#include <cstdint>

typedef unsigned short u16;
typedef unsigned int   u32;

typedef __attribute__((ext_vector_type(8))) short bf16x8;
typedef __attribute__((ext_vector_type(4))) float f32x4;

#define DEV __device__ __forceinline__

static constexpr int HP = 66, WP = 66;   // padded spatial

DEV u16 f2bf(float f) {
  u32 u = __float_as_uint(f);
  u32 r = (u + 0x7fffu + ((u >> 16) & 1u)) >> 16;
  return (u16)r;
}
DEV float bf2f(u16 v) { return __uint_as_float((u32)v << 16); }

DEV void gload_lds16(const void* g, void* s) {
  __builtin_amdgcn_global_load_lds(
      (const __attribute__((address_space(1))) void*)g,
      (__attribute__((address_space(3))) void*)s, 16, 0, 0);
}

// ---------------- weight repack: OIHW fp32 -> [co][(ky*3+kx)*Cin+ci] bf16 ----------
__global__ __launch_bounds__(256) void repack_w_kernel(const float* __restrict__ src,
                                                       u16* __restrict__ dst,
                                                       int Cin, int K, int total,
                                                       int ksq, int kdim) {
  for (int idx = blockIdx.x * 256 + threadIdx.x; idx < total; idx += gridDim.x * 256) {
    int co = idx / K;
    int r  = idx - co * K;
    int s  = r / Cin;
    int ci = r - s * Cin;
    int ky = s / kdim, kx = s - ky * kdim;
    dst[idx] = f2bf(src[(co * Cin + ci) * ksq + ky * kdim + kx]);
  }
}

// ---------------- SS_T[i][o] = sum_{kh,kw} mod_w[o][i]^2 ----------------
__global__ __launch_bounds__(256) void modw_ss_kernel(const float* __restrict__ w,
                                                      float* __restrict__ SS_T) {
  int o = blockIdx.x, i = threadIdx.x;
  const float* p = w + (size_t)(o * 256 + i) * 9;
  float s = 0.f;
#pragma unroll
  for (int k = 0; k < 9; ++k) s += p[k] * p[k];
  SS_T[i * 256 + o] = s;
}

// ---------------- mvec[b][i] = style . style_w[i] + style_b[i] + 1 ----------------
__global__ __launch_bounds__(256) void style_mvec_kernel(const float* __restrict__ style,
                                                         const float* __restrict__ style_w,
                                                         const float* __restrict__ style_b,
                                                         float* __restrict__ mvec) {
  __shared__ float st[512];
  int b = blockIdx.x, t = threadIdx.x;
  for (int k = t; k < 512; k += 256) st[k] = style[b * 512 + k];
  __syncthreads();
  const float4* wr = (const float4*)(style_w + t * 512);
  float acc = 0.f;
  for (int k = 0; k < 128; ++k) {
    float4 w4 = wr[k];
    acc += w4.x * st[k*4] + w4.y * st[k*4+1] + w4.z * st[k*4+2] + w4.w * st[k*4+3];
  }
  mvec[b * 256 + t] = acc + style_b[t] + 1.f;
}

// ---------------- dvec[b][o] = rsqrt(sum_i mvec[b][i]^2 * SS_T[i][o] + eps) ---------
__global__ __launch_bounds__(256) void demod_kernel(const float* __restrict__ mvec,
                                                    const float* __restrict__ SS_T,
                                                    float* __restrict__ dvec) {
  __shared__ float m2[256];
  int b = blockIdx.x, t = threadIdx.x;
  float mv = mvec[b * 256 + t];
  m2[t] = mv * mv;
  __syncthreads();
  float acc = 0.f;
  for (int i = 0; i < 256; ++i) acc += m2[i] * SS_T[i * 256 + t];
  dvec[b * 256 + t] = rsqrtf(acc + 1e-8f);
}

// ---------------- scTb[b][co][ci] = sc_w[co][ci] / dvec[b][co]  (bf16) --------------
__global__ __launch_bounds__(256) void scale_sc_kernel(const float* __restrict__ sc_w,
                                                       const float* __restrict__ dvec,
                                                       u16* __restrict__ scTb) {
  int idx = blockIdx.x * 256 + threadIdx.x;   // 32*256*128 total
  int ci = idx & 127;
  int co = (idx >> 7) & 255;
  int b  = idx >> 15;
  scTb[idx] = f2bf(sc_w[co * 128 + ci] / dvec[b * 256 + co]);
}

// ---------------- tb2[b][co] = swish(temb[b]) . temb_w[co] + temb_b + conv1_b -------
__global__ __launch_bounds__(256) void temb_proj_kernel(const float* __restrict__ temb,
                                                        const float* __restrict__ temb_w,
                                                        const float* __restrict__ temb_b,
                                                        const float* __restrict__ conv1_b,
                                                        float* __restrict__ tb2) {
  __shared__ float sw[512];
  int b = blockIdx.x, t = threadIdx.x;
  for (int k = t; k < 512; k += 256) {
    float v = temb[b * 512 + k];
    sw[k] = v / (1.f + __expf(-v));
  }
  __syncthreads();
  const float4* wr = (const float4*)(temb_w + t * 512);
  float acc = 0.f;
  for (int k = 0; k < 128; ++k) {
    float4 w4 = wr[k];
    acc += w4.x * sw[k*4] + w4.y * sw[k*4+1] + w4.z * sw[k*4+2] + w4.w * sw[k*4+3];
  }
  tb2[b * 256 + t] = acc + temb_b[t] + conv1_b[t];
}

// ---------------- halo zero: clear only border pixels of padded NHWC buffer ---------
template <int C>
__global__ __launch_bounds__(256) void halo_zero_kernel(u16* __restrict__ buf) {
  int idx = blockIdx.x * 256 + threadIdx.x;
  const int GR = C / 8;
  if (idx >= 32 * 260 * GR) return;
  int g = idx % GR;
  int p = (idx / GR) % 260;
  int b = idx / (GR * 260);
  int y, x;
  if (p < 66)       { y = 0;        x = p; }
  else if (p < 132) { y = 65;       x = p - 66; }
  else if (p < 196) { y = p - 131;  x = 0; }
  else              { y = p - 195;  x = 65; }
  uint4 z; z.x = 0; z.y = 0; z.z = 0; z.w = 0;
  *(uint4*)(buf + (((size_t)b * HP + y) * WP + x) * C + g * 8) = z;
}

// ---------------- GN1 stats ----------------
__global__ __launch_bounds__(256) void gn1_stats_kernel(const float* __restrict__ x,
                                                        float2* __restrict__ st1) {
  int bg = blockIdx.x;
  const float4* p = (const float4*)(x + (size_t)bg * 16384);
  float s = 0.f, s2 = 0.f;
  for (int i = threadIdx.x; i < 4096; i += 256) {
    float4 v = p[i];
    s  += v.x + v.y + v.z + v.w;
    s2 += v.x*v.x + v.y*v.y + v.z*v.z + v.w*v.w;
  }
  for (int d = 32; d; d >>= 1) { s += __shfl_down(s, d); s2 += __shfl_down(s2, d); }
  __shared__ float red[2][4];
  if ((threadIdx.x & 63) == 0) { red[0][threadIdx.x >> 6] = s; red[1][threadIdx.x >> 6] = s2; }
  __syncthreads();
  if (threadIdx.x == 0) {
    s  = red[0][0] + red[0][1] + red[0][2] + red[0][3];
    s2 = red[1][0] + red[1][1] + red[1][2] + red[1][3];
    float mean = s / 16384.f;
    float var  = s2 / 16384.f - mean * mean;
    st1[bg] = make_float2(mean, rsqrtf(var + 1e-5f));
  }
}

// ---------------- GN1 apply + swish -> act1p (padded NHWC bf16); also x -> xh NHWC --
__global__ __launch_bounds__(256) void gn1_apply_kernel(const float* __restrict__ x,
                                                        const float2* __restrict__ st1,
                                                        const float* __restrict__ g1,
                                                        const float* __restrict__ b1,
                                                        u16* __restrict__ act1p,
                                                        u16* __restrict__ xh) {
  __shared__ float xs[128][65];
  int blk = blockIdx.x;
  int b = blk >> 6, y = blk & 63;
  int t = threadIdx.x;
#pragma unroll 8
  for (int pass = 0; pass < 32; ++pass) {
    int c = pass * 4 + (t >> 6);
    xs[c][t & 63] = x[(((size_t)b * 128 + c) * 64 + y) * 64 + (t & 63)];
  }
  __syncthreads();
  for (int pass = 0; pass < 32; ++pass) {
    int xc = pass * 2 + (t >> 7);
    int c  = t & 127;
    float v = xs[c][xc];
    float2 ms = st1[b * 32 + (c >> 2)];
    float vn = (v - ms.x) * ms.y * g1[c] + b1[c];
    float sw = vn / (1.f + __expf(-vn));
    act1p[(((size_t)b * HP + (y + 1)) * WP + (xc + 1)) * 128 + c] = f2bf(sw);
    xh[(((size_t)b * 64 + y) * 64 + xc) * 128 + c] = f2bf(v);
  }
}

// ---------------- GN2 final: totals -> mean/rsqrt ----------------
__global__ void gn2_final_kernel(const float* __restrict__ st2sum, float2* __restrict__ st2) {
  int idx = blockIdx.x * 256 + threadIdx.x;
  if (idx >= 1024) return;
  float s  = st2sum[idx * 2];
  float s2 = st2sum[idx * 2 + 1];
  float mean = s / 32768.f;
  float var  = s2 / 32768.f - mean * mean;
  st2[idx] = make_float2(mean, rsqrtf(var + 1e-5f));
}

// ------- GN2 apply + swish + input-channel modulation: h1 -> act2p (padded NHWC) ----
__global__ __launch_bounds__(256) void gn2_apply_kernel(const u16* __restrict__ h1,
                                                        const float2* __restrict__ st2,
                                                        const float* __restrict__ g2,
                                                        const float* __restrict__ b2,
                                                        const float* __restrict__ mvec,
                                                        u16* __restrict__ act2p) {
  int idx = blockIdx.x * 256 + threadIdx.x;  // granule id
  int gpix = idx >> 5;
  int gi = idx & 31;
  int c0 = gi * 8;
  int b = gpix >> 12, y = (gpix >> 6) & 63, x = gpix & 63;
  uint4 raw = *(const uint4*)(h1 + (size_t)gpix * 256 + c0);
  const u16* rs = (const u16*)&raw;
  float2 ms = st2[b * 32 + gi];
  const float* mv = mvec + b * 256 + c0;
  u16 outp[8];
#pragma unroll
  for (int e = 0; e < 8; ++e) {
    float v  = bf2f(rs[e]);
    float vn = (v - ms.x) * ms.y * g2[c0 + e] + b2[c0 + e];
    float sw = vn / (1.f + __expf(-vn));
    outp[e] = f2bf(sw * mv[e]);
  }
  *(uint4*)(act2p + (((size_t)b * HP + (y + 1)) * WP + (x + 1)) * 256 + c0) = *(const uint4*)outp;
}

// ---------- implicit-GEMM conv: 256x256 tile, 8 waves, BK=64, 4-phase schedule ------
// Pre-barrier ds_reads (m201 ordering): phase = { ds_read frags (published >=1
// barrier ago) ; stage next half ; vmcnt(4) ; barrier ; lgkmcnt(0) ; MFMA }.
// vmcnt(4) = 2 halves in flight; placed at phases 0,1,3 (none at 2).
// XCD-chunked block swizzle: each XCD owns 64 contiguous m-tiles (4 images).
template <int MODE>
__global__ __launch_bounds__(512, 2) void igemm_kernel(const u16* __restrict__ act,
                                                       const u16* __restrict__ wT,
                                                       const float* __restrict__ epi,
                                                       const u16* __restrict__ xh,
                                                       const u16* __restrict__ scTb,
                                                       const float* __restrict__ sc_b,
                                                       u16* __restrict__ h1out,
                                                       float* __restrict__ fout,
                                                       float* __restrict__ st2sum) {
  constexpr int CIN    = (MODE == 0) ? 128 : 256;
  constexpr int NSUB   = CIN / 64;
  constexpr int KW     = CIN * 9;
  constexpr int NKMAIN = KW / 64;                 // 18 / 36
  constexpr int NKT    = (MODE == 2) ? NKMAIN + 2 : NKMAIN;

  __shared__ __align__(16) unsigned char lds[131072];
  const int tid  = threadIdx.x;
  const int wave = tid >> 6, lane = tid & 63;
  const int wm = wave >> 2, wn = wave & 3;        // 2 x 4 waves
  const int swz = ((blockIdx.x & 7) << 6) | (blockIdx.x >> 3);   // XCD-chunked
  const int m_base = swz * 256;
  const int bimg = m_base >> 12;
  const int ln = lane & 15, l4 = lane >> 4;

  // staging lane constants
  const int srow = lane >> 3;                     // 0..7
  const int glog = (lane & 7) ^ srow;             // pre-swizzled source granule

  u32 pixA[2][2], pixX[2][2], rowB[2][2], rowS[2][2];
#pragma unroll
  for (int j = 0; j < 2; ++j)
#pragma unroll
    for (int h = 0; h < 2; ++h) {
      int mlocal = (wave & 3) * 16 + j * 8 + srow + h * 64 + (wave >> 2) * 128;
      int m = m_base + mlocal;
      int y = (m >> 6) & 63, x = m & 63;
      pixA[j][h] = (u32)((bimg * HP + y) * WP + x) * CIN + glog * 8;
      if (MODE == 2) pixX[j][h] = (u32)m * 128 + glog * 8;
      int co = (wave >> 1) * 64 + h * 32 + (wave & 1) * 16 + j * 8 + srow;
      rowB[j][h] = (u32)co * KW + glog * 8;
      if (MODE == 2) rowS[j][h] = (u32)(bimg * 256 + co) * 128 + glog * 8;
    }

  f32x4 acc[8][4];
#pragma unroll
  for (int i = 0; i < 8; ++i)
#pragma unroll
    for (int j = 0; j < 4; ++j) acc[i][j] = (f32x4){0.f, 0.f, 0.f, 0.f};

  auto stageA = [&](int kt, int h, int buf) {
    unsigned char* dst = lds + buf * 65536 + h * 16384 + wave * 2048;
    if (MODE == 2 && kt >= NKMAIN) {
      u32 ko = (u32)(kt - NKMAIN) * 64;
      gload_lds16(xh + pixX[0][h] + ko, dst);
      gload_lds16(xh + pixX[1][h] + ko, dst + 1024);
    } else {
      int tap = kt / NSUB;
      int kin = (kt - tap * NSUB) * 64;
      int ky = tap / 3, kx = tap - ky * 3;
      u32 ko = (u32)((ky * WP + kx) * CIN + kin);
      gload_lds16(act + pixA[0][h] + ko, dst);
      gload_lds16(act + pixA[1][h] + ko, dst + 1024);
    }
  };
  auto stageB = [&](int kt, int g, int buf) {
    unsigned char* dst = lds + buf * 65536 + 32768 + g * 16384 + wave * 2048;
    if (MODE == 2 && kt >= NKMAIN) {
      u32 ko = (u32)(kt - NKMAIN) * 64;
      gload_lds16(scTb + rowS[0][g] + ko, dst);
      gload_lds16(scTb + rowS[1][g] + ko, dst + 1024);
    } else {
      u32 ko = (u32)kt * 64;
      gload_lds16(wT + rowB[0][g] + ko, dst);
      gload_lds16(wT + rowB[1][g] + ko, dst + 1024);
    }
  };

  bf16x8 af[8], bf[4];
  auto ldA = [&](int h, int buf) {
    const unsigned char* As = lds + buf * 65536;
#pragma unroll
    for (int f = 0; f < 4; ++f)
#pragma unroll
      for (int kk = 0; kk < 2; ++kk) {
        int lr = h * 128 + wm * 64 + f * 16 + ln;
        int gr = (kk * 4 + l4) ^ (ln & 7);
        af[f * 2 + kk] = *(const bf16x8*)(As + lr * 128 + gr * 16);
      }
  };
  auto ldB = [&](int g, int buf) {
    const unsigned char* Bs = lds + buf * 65536 + 32768;
#pragma unroll
    for (int f1 = 0; f1 < 2; ++f1)
#pragma unroll
      for (int kk = 0; kk < 2; ++kk) {
        int lr = g * 128 + wn * 32 + f1 * 16 + ln;
        int gr = (kk * 4 + l4) ^ (ln & 7);
        bf[f1 * 2 + kk] = *(const bf16x8*)(Bs + lr * 128 + gr * 16);
      }
  };
  auto mmac = [&](int h, int g) {
    __builtin_amdgcn_s_setprio(1);
#pragma unroll
    for (int f = 0; f < 4; ++f)
#pragma unroll
      for (int f1 = 0; f1 < 2; ++f1)
#pragma unroll
        for (int kk = 0; kk < 2; ++kk)
          acc[h * 4 + f][g * 2 + f1] = __builtin_amdgcn_mfma_f32_16x16x32_bf16(
              af[f * 2 + kk], bf[f1 * 2 + kk], acc[h * 4 + f][g * 2 + f1], 0, 0, 0);
    __builtin_amdgcn_s_setprio(0);
  };

#define SB() __builtin_amdgcn_sched_barrier(0)
#define LGKM0() asm volatile("s_waitcnt lgkmcnt(0)" ::: "memory")

  // prologue: stage tile 0 in consumption order; publish Ah0,Bg0
  stageA(0, 0, 0); stageB(0, 0, 0); stageB(0, 1, 0); stageA(0, 1, 0);
  asm volatile("s_waitcnt vmcnt(4)" ::: "memory");
  __builtin_amdgcn_s_barrier();

#pragma unroll 2
  for (int kt = 0; kt < NKT; ++kt) {
    const int cur = kt & 1, nxt = cur ^ 1;
    const bool more = (kt + 1 < NKT);
    // ---- ph0: (h0,g0); stage Ah0(kt+1); publish Bg1(kt) ----
    ldB(0, cur); ldA(0, cur); SB();
    if (more) { stageA(kt + 1, 0, nxt);
                asm volatile("s_waitcnt vmcnt(4)" ::: "memory"); }
    else      { asm volatile("s_waitcnt vmcnt(2)" ::: "memory"); }
    __builtin_amdgcn_s_barrier();
    LGKM0(); SB();
    mmac(0, 0);
    // ---- ph1: (h0,g1); stage Bg0(kt+1); publish Ah1(kt) ----
    ldB(1, cur); SB();
    if (more) { stageB(kt + 1, 0, nxt);
                asm volatile("s_waitcnt vmcnt(4)" ::: "memory"); }
    else      { asm volatile("s_waitcnt vmcnt(0)" ::: "memory"); }
    __builtin_amdgcn_s_barrier();
    LGKM0(); SB();
    mmac(0, 1);
    // ---- ph2: (h1,g1); stage Bg1(kt+1); nothing to publish ----
    ldA(1, cur); SB();
    if (more) stageB(kt + 1, 1, nxt);
    __builtin_amdgcn_s_barrier();
    LGKM0(); SB();
    mmac(1, 1);
    // ---- ph3: (h1,g0) re-read Bg0; stage Ah1(kt+1); publish Ah0,Bg0(kt+1) ----
    ldB(0, cur); SB();
    if (more) { stageA(kt + 1, 1, nxt);
                asm volatile("s_waitcnt vmcnt(4)" ::: "memory"); }
    __builtin_amdgcn_s_barrier();
    LGKM0(); SB();
    mmac(1, 0);
  }
#undef SB
#undef LGKM0

  if (MODE == 0) {
    const float* tbrow = epi + bimg * 256;
    float ps[4], ps2[4];
#pragma unroll
    for (int fn = 0; fn < 4; ++fn) { ps[fn] = 0.f; ps2[fn] = 0.f; }
#pragma unroll
    for (int fm = 0; fm < 8; ++fm)
#pragma unroll
      for (int fn = 0; fn < 4; ++fn) {
        int co = wn * 64 + fn * 16 + ln;
        float add = tbrow[co];
#pragma unroll
        for (int i = 0; i < 4; ++i) {
          int m = m_base + wm * 128 + fm * 16 + (l4 << 2) + i;
          float v = acc[fm][fn][i] + add;
          h1out[(size_t)m * 256 + co] = f2bf(v);
          ps[fn] += v; ps2[fn] += v * v;
        }
      }
    // fused GN2 partial stats: reduce over lanes sharing a channel-group
#pragma unroll
    for (int fn = 0; fn < 4; ++fn) {
      float s = ps[fn], s2 = ps2[fn];
      s += __shfl_xor(s, 1);  s2 += __shfl_xor(s2, 1);
      s += __shfl_xor(s, 2);  s2 += __shfl_xor(s2, 2);
      s += __shfl_xor(s, 4);  s2 += __shfl_xor(s2, 4);
      s += __shfl_xor(s, 16); s2 += __shfl_xor(s2, 16);
      s += __shfl_xor(s, 32); s2 += __shfl_xor(s2, 32);
      if ((lane & 55) == 0) {                 // lanes 0 and 8
        int g = wn * 8 + fn * 2 + (ln >> 3);
        atomicAdd(&st2sum[bimg * 64 + g * 2 + 0], s);
        atomicAdd(&st2sum[bimg * 64 + g * 2 + 1], s2);
      }
    }
  } else {
    float* tile = (float*)lds;              // [64][257] f32
    const int pixb = m_base & 4095;
#pragma unroll
    for (int c = 0; c < 4; ++c) {
      __syncthreads();
      if (wn == c) {
#pragma unroll
        for (int fn = 0; fn < 4; ++fn) {
          int nl = fn * 16 + ln;
          int co = c * 64 + nl;
          float dsc = epi[bimg * 256 + co];
          float scb = sc_b[co];
#pragma unroll
          for (int fm = 0; fm < 8; ++fm)
#pragma unroll
            for (int i = 0; i < 4; ++i) {
              int ml = wm * 128 + fm * 16 + (l4 << 2) + i;
              tile[nl * 257 + ml] = acc[fm][fn][i] * dsc + scb;
            }
        }
      }
      __syncthreads();
#pragma unroll 4
      for (int it = 0; it < 32; ++it) {
        int lin = it * 512 + tid;
        int co_l = lin >> 8, ml = lin & 255;
        fout[((size_t)(bimg * 256 + c * 64 + co_l)) * 4096 + pixb + ml] =
            tile[co_l * 257 + ml];
      }
    }
  }
}

// ------------------------------- launch -------------------------------
extern "C" void kernel_launch(void* const* d_in, const int* in_sizes, int n_in,
                              void* d_out, int out_size, void* d_ws, size_t ws_size,
                              hipStream_t stream) {
  const float* x       = (const float*)d_in[0];
  const float* temb    = (const float*)d_in[1];
  const float* style   = (const float*)d_in[2];
  const float* gn1_g   = (const float*)d_in[3];
  const float* gn1_b   = (const float*)d_in[4];
  const float* conv1_w = (const float*)d_in[5];
  const float* conv1_b = (const float*)d_in[6];
  const float* temb_w  = (const float*)d_in[7];
  const float* temb_b  = (const float*)d_in[8];
  const float* gn2_g   = (const float*)d_in[9];
  const float* gn2_b   = (const float*)d_in[10];
  const float* style_w = (const float*)d_in[11];
  const float* style_b = (const float*)d_in[12];
  const float* mod_w   = (const float*)d_in[13];
  const float* sc_w    = (const float*)d_in[14];
  const float* sc_b    = (const float*)d_in[15];
  float* out = (float*)d_out;
  char* ws = (char*)d_ws;

  size_t o = 0;
  auto alloc = [&](size_t bytes) { size_t r = o; o += (bytes + 255) & ~(size_t)255; return r; };
  const size_t act1p_bytes = (size_t)32 * HP * WP * 128 * 2;
  const size_t xh_bytes    = (size_t)32 * 64 * 64 * 128 * 2;
  const size_t h1_bytes    = (size_t)32 * 4096 * 256 * 2;
  const size_t act2p_bytes = (size_t)32 * HP * WP * 256 * 2;
  size_t o_act1p = alloc(act1p_bytes);
  size_t o_xh    = alloc(xh_bytes);
  size_t o_h1    = alloc(h1_bytes);
  size_t o_act2p = alloc(act2p_bytes);
  size_t o_w1T   = alloc((size_t)256 * 1152 * 2);
  size_t o_wmT   = alloc((size_t)256 * 2304 * 2);
  size_t o_scTb  = alloc((size_t)32 * 256 * 128 * 2);
  size_t o_tb2   = alloc(8192 * 4);
  size_t o_mvec  = alloc(8192 * 4);
  size_t o_dvec  = alloc(8192 * 4);
  size_t o_SS    = alloc((size_t)256 * 256 * 4);
  size_t o_st1   = alloc(1024 * 8);
  size_t o_st2   = alloc(1024 * 8);
  size_t o_s2sum = alloc(32 * 32 * 2 * 4);
  if (ws_size < o) return;

  u16*    act1p = (u16*)(ws + o_act1p);
  u16*    xh    = (u16*)(ws + o_xh);
  u16*    h1    = (u16*)(ws + o_h1);
  u16*    act2p = (u16*)(ws + o_act2p);
  u16*    w1T   = (u16*)(ws + o_w1T);
  u16*    wmT   = (u16*)(ws + o_wmT);
  u16*    scTb  = (u16*)(ws + o_scTb);
  float*  tb2   = (float*)(ws + o_tb2);
  float*  mvec  = (float*)(ws + o_mvec);
  float*  dvec  = (float*)(ws + o_dvec);
  float*  SS_T  = (float*)(ws + o_SS);
  float2* st1   = (float2*)(ws + o_st1);
  float2* st2   = (float2*)(ws + o_st2);
  float*  s2sum = (float*)(ws + o_s2sum);

  // zero halo borders + GN2 atomic accumulator
  halo_zero_kernel<128><<<(32 * 260 * 16 + 255) / 256, 256, 0, stream>>>(act1p);
  halo_zero_kernel<256><<<(32 * 260 * 32 + 255) / 256, 256, 0, stream>>>(act2p);
  hipMemsetAsync(s2sum, 0, 32 * 32 * 2 * 4, stream);

  repack_w_kernel<<<1152, 256, 0, stream>>>(conv1_w, w1T, 128, 1152, 256 * 1152, 9, 3);
  repack_w_kernel<<<2304, 256, 0, stream>>>(mod_w, wmT, 256, 2304, 256 * 2304, 9, 3);
  modw_ss_kernel<<<256, 256, 0, stream>>>(mod_w, SS_T);
  temb_proj_kernel<<<32, 256, 0, stream>>>(temb, temb_w, temb_b, conv1_b, tb2);
  style_mvec_kernel<<<32, 256, 0, stream>>>(style, style_w, style_b, mvec);
  demod_kernel<<<32, 256, 0, stream>>>(mvec, SS_T, dvec);
  scale_sc_kernel<<<4096, 256, 0, stream>>>(sc_w, dvec, scTb);
  gn1_stats_kernel<<<1024, 256, 0, stream>>>(x, st1);
  gn1_apply_kernel<<<2048, 256, 0, stream>>>(x, st1, gn1_g, gn1_b, act1p, xh);

  igemm_kernel<0><<<512, 512, 0, stream>>>(act1p, w1T, tb2, nullptr, nullptr,
                                           nullptr, h1, nullptr, s2sum);

  gn2_final_kernel<<<4, 256, 0, stream>>>(s2sum, st2);
  gn2_apply_kernel<<<16384, 256, 0, stream>>>(h1, st2, gn2_g, gn2_b, mvec, act2p);

  igemm_kernel<2><<<512, 512, 0, stream>>>(act2p, wmT, dvec, xh, scTb,
                                           sc_b, nullptr, out, nullptr);
}

// Round 7
// 375.014 us; speedup vs baseline: 1.4350x; 1.4350x over previous
//
#include <hip/hip_runtime.h>
#include <cstdint>

typedef unsigned short u16;
typedef unsigned int   u32;

typedef __attribute__((ext_vector_type(8))) short bf16x8;
typedef __attribute__((ext_vector_type(4))) float f32x4;

#define DEV __device__ __forceinline__

static constexpr int HP = 66, WP = 66;   // padded spatial

DEV u16 f2bf(float f) {
  u32 u = __float_as_uint(f);
  u32 r = (u + 0x7fffu + ((u >> 16) & 1u)) >> 16;
  return (u16)r;
}
DEV float bf2f(u16 v) { return __uint_as_float((u32)v << 16); }

DEV void gload_lds16(const void* g, void* s) {
  __builtin_amdgcn_global_load_lds(
      (const __attribute__((address_space(1))) void*)g,
      (__attribute__((address_space(3))) void*)s, 16, 0, 0);
}

// ---------------- weight repack: OIHW fp32 -> [co][(ky*3+kx)*Cin+ci] bf16 ----------
__global__ __launch_bounds__(256) void repack_w_kernel(const float* __restrict__ src,
                                                       u16* __restrict__ dst,
                                                       int Cin, int K, int total,
                                                       int ksq, int kdim) {
  for (int idx = blockIdx.x * 256 + threadIdx.x; idx < total; idx += gridDim.x * 256) {
    int co = idx / K;
    int r  = idx - co * K;
    int s  = r / Cin;
    int ci = r - s * Cin;
    int ky = s / kdim, kx = s - ky * kdim;
    dst[idx] = f2bf(src[(co * Cin + ci) * ksq + ky * kdim + kx]);
  }
}

// ---------------- SS_T[i][o] = sum_{kh,kw} mod_w[o][i]^2 ----------------
__global__ __launch_bounds__(256) void modw_ss_kernel(const float* __restrict__ w,
                                                      float* __restrict__ SS_T) {
  int o = blockIdx.x, i = threadIdx.x;
  const float* p = w + (size_t)(o * 256 + i) * 9;
  float s = 0.f;
#pragma unroll
  for (int k = 0; k < 9; ++k) s += p[k] * p[k];
  SS_T[i * 256 + o] = s;
}

// ---------------- mvec[b][i] = style . style_w[i] + style_b[i] + 1 ----------------
__global__ __launch_bounds__(256) void style_mvec_kernel(const float* __restrict__ style,
                                                         const float* __restrict__ style_w,
                                                         const float* __restrict__ style_b,
                                                         float* __restrict__ mvec) {
  __shared__ float st[512];
  int b = blockIdx.x, t = threadIdx.x;
  for (int k = t; k < 512; k += 256) st[k] = style[b * 512 + k];
  __syncthreads();
  const float4* wr = (const float4*)(style_w + t * 512);
  float acc = 0.f;
  for (int k = 0; k < 128; ++k) {
    float4 w4 = wr[k];
    acc += w4.x * st[k*4] + w4.y * st[k*4+1] + w4.z * st[k*4+2] + w4.w * st[k*4+3];
  }
  mvec[b * 256 + t] = acc + style_b[t] + 1.f;
}

// ---------------- dvec[b][o] = rsqrt(sum_i mvec[b][i]^2 * SS_T[i][o] + eps) ---------
__global__ __launch_bounds__(256) void demod_kernel(const float* __restrict__ mvec,
                                                    const float* __restrict__ SS_T,
                                                    float* __restrict__ dvec) {
  __shared__ float m2[256];
  int b = blockIdx.x, t = threadIdx.x;
  float mv = mvec[b * 256 + t];
  m2[t] = mv * mv;
  __syncthreads();
  float acc = 0.f;
  for (int i = 0; i < 256; ++i) acc += m2[i] * SS_T[i * 256 + t];
  dvec[b * 256 + t] = rsqrtf(acc + 1e-8f);
}

// ---------------- scTb[b][co][ci] = sc_w[co][ci] / dvec[b][co]  (bf16) --------------
__global__ __launch_bounds__(256) void scale_sc_kernel(const float* __restrict__ sc_w,
                                                       const float* __restrict__ dvec,
                                                       u16* __restrict__ scTb) {
  int idx = blockIdx.x * 256 + threadIdx.x;   // 32*256*128 total
  int ci = idx & 127;
  int co = (idx >> 7) & 255;
  int b  = idx >> 15;
  scTb[idx] = f2bf(sc_w[co * 128 + ci] / dvec[b * 256 + co]);
}

// ---------------- tb2[b][co] = swish(temb[b]) . temb_w[co] + temb_b + conv1_b -------
__global__ __launch_bounds__(256) void temb_proj_kernel(const float* __restrict__ temb,
                                                        const float* __restrict__ temb_w,
                                                        const float* __restrict__ temb_b,
                                                        const float* __restrict__ conv1_b,
                                                        float* __restrict__ tb2) {
  __shared__ float sw[512];
  int b = blockIdx.x, t = threadIdx.x;
  for (int k = t; k < 512; k += 256) {
    float v = temb[b * 512 + k];
    sw[k] = v / (1.f + __expf(-v));
  }
  __syncthreads();
  const float4* wr = (const float4*)(temb_w + t * 512);
  float acc = 0.f;
  for (int k = 0; k < 128; ++k) {
    float4 w4 = wr[k];
    acc += w4.x * sw[k*4] + w4.y * sw[k*4+1] + w4.z * sw[k*4+2] + w4.w * sw[k*4+3];
  }
  tb2[b * 256 + t] = acc + temb_b[t] + conv1_b[t];
}

// ---------------- halo zero: clear only border pixels of padded NHWC buffer ---------
template <int C>
__global__ __launch_bounds__(256) void halo_zero_kernel(u16* __restrict__ buf) {
  int idx = blockIdx.x * 256 + threadIdx.x;
  const int GR = C / 8;
  if (idx >= 32 * 260 * GR) return;
  int g = idx % GR;
  int p = (idx / GR) % 260;
  int b = idx / (GR * 260);
  int y, x;
  if (p < 66)       { y = 0;        x = p; }
  else if (p < 132) { y = 65;       x = p - 66; }
  else if (p < 196) { y = p - 131;  x = 0; }
  else              { y = p - 195;  x = 65; }
  uint4 z; z.x = 0; z.y = 0; z.z = 0; z.w = 0;
  *(uint4*)(buf + (((size_t)b * HP + y) * WP + x) * C + g * 8) = z;
}

// ---------------- GN1 stats ----------------
__global__ __launch_bounds__(256) void gn1_stats_kernel(const float* __restrict__ x,
                                                        float2* __restrict__ st1) {
  int bg = blockIdx.x;
  const float4* p = (const float4*)(x + (size_t)bg * 16384);
  float s = 0.f, s2 = 0.f;
  for (int i = threadIdx.x; i < 4096; i += 256) {
    float4 v = p[i];
    s  += v.x + v.y + v.z + v.w;
    s2 += v.x*v.x + v.y*v.y + v.z*v.z + v.w*v.w;
  }
  for (int d = 32; d; d >>= 1) { s += __shfl_down(s, d); s2 += __shfl_down(s2, d); }
  __shared__ float red[2][4];
  if ((threadIdx.x & 63) == 0) { red[0][threadIdx.x >> 6] = s; red[1][threadIdx.x >> 6] = s2; }
  __syncthreads();
  if (threadIdx.x == 0) {
    s  = red[0][0] + red[0][1] + red[0][2] + red[0][3];
    s2 = red[1][0] + red[1][1] + red[1][2] + red[1][3];
    float mean = s / 16384.f;
    float var  = s2 / 16384.f - mean * mean;
    st1[bg] = make_float2(mean, rsqrtf(var + 1e-5f));
  }
}

// ---------------- GN1 apply + swish -> act1p (padded NHWC bf16); also x -> xh NHWC --
__global__ __launch_bounds__(256) void gn1_apply_kernel(const float* __restrict__ x,
                                                        const float2* __restrict__ st1,
                                                        const float* __restrict__ g1,
                                                        const float* __restrict__ b1,
                                                        u16* __restrict__ act1p,
                                                        u16* __restrict__ xh) {
  __shared__ float xs[128][65];
  int blk = blockIdx.x;
  int b = blk >> 6, y = blk & 63;
  int t = threadIdx.x;
#pragma unroll 8
  for (int pass = 0; pass < 32; ++pass) {
    int c = pass * 4 + (t >> 6);
    xs[c][t & 63] = x[(((size_t)b * 128 + c) * 64 + y) * 64 + (t & 63)];
  }
  __syncthreads();
  for (int pass = 0; pass < 32; ++pass) {
    int xc = pass * 2 + (t >> 7);
    int c  = t & 127;
    float v = xs[c][xc];
    float2 ms = st1[b * 32 + (c >> 2)];
    float vn = (v - ms.x) * ms.y * g1[c] + b1[c];
    float sw = vn / (1.f + __expf(-vn));
    act1p[(((size_t)b * HP + (y + 1)) * WP + (xc + 1)) * 128 + c] = f2bf(sw);
    xh[(((size_t)b * 64 + y) * 64 + xc) * 128 + c] = f2bf(v);
  }
}

// ---------------- GN2 final: fused totals -> mean/rsqrt ----------------
__global__ void gn2_final_kernel(const float* __restrict__ st2sum, float2* __restrict__ st2) {
  int idx = blockIdx.x * 256 + threadIdx.x;
  if (idx >= 1024) return;
  float s  = st2sum[idx * 2];
  float s2 = st2sum[idx * 2 + 1];
  float mean = s / 32768.f;
  float var  = s2 / 32768.f - mean * mean;
  st2[idx] = make_float2(mean, rsqrtf(var + 1e-5f));
}

// ------- GN2 apply + swish + input-channel modulation: h1 -> act2p (padded NHWC) ----
__global__ __launch_bounds__(256) void gn2_apply_kernel(const u16* __restrict__ h1,
                                                        const float2* __restrict__ st2,
                                                        const float* __restrict__ g2,
                                                        const float* __restrict__ b2,
                                                        const float* __restrict__ mvec,
                                                        u16* __restrict__ act2p) {
  int idx = blockIdx.x * 256 + threadIdx.x;  // granule id
  int gpix = idx >> 5;
  int gi = idx & 31;
  int c0 = gi * 8;
  int b = gpix >> 12, y = (gpix >> 6) & 63, x = gpix & 63;
  uint4 raw = *(const uint4*)(h1 + (size_t)gpix * 256 + c0);
  const u16* rs = (const u16*)&raw;
  float2 ms = st2[b * 32 + gi];
  const float* mv = mvec + b * 256 + c0;
  u16 outp[8];
#pragma unroll
  for (int e = 0; e < 8; ++e) {
    float v  = bf2f(rs[e]);
    float vn = (v - ms.x) * ms.y * g2[c0 + e] + b2[c0 + e];
    float sw = vn / (1.f + __expf(-vn));
    outp[e] = f2bf(sw * mv[e]);
  }
  *(uint4*)(act2p + (((size_t)b * HP + (y + 1)) * WP + (x + 1)) * 256 + c0) = *(const uint4*)outp;
}

// ---------- implicit-GEMM conv: 256x256 tile, 8 waves, BK=64, 4-phase schedule ------
// (round-5 proven schedule: per phase = stage next half -> vmcnt(6) -> barrier ->
//  ds_read frags -> MFMA; 3 half-tiles in flight; linear block order.)
// MODE 0: conv1  (Cin=128, 3x3) -> h1 bf16 NHWC, epi=tb2; fused GN2 partial stats.
// MODE 2: modconv(Cin=256, 3x3) + fused 1x1 shortcut -> d_out NCHW fp32.
template <int MODE>
__global__ __launch_bounds__(512, 2) void igemm_kernel(const u16* __restrict__ act,
                                                       const u16* __restrict__ wT,
                                                       const float* __restrict__ epi,
                                                       const u16* __restrict__ xh,
                                                       const u16* __restrict__ scTb,
                                                       const float* __restrict__ sc_b,
                                                       u16* __restrict__ h1out,
                                                       float* __restrict__ fout,
                                                       float* __restrict__ st2sum) {
  constexpr int CIN    = (MODE == 0) ? 128 : 256;
  constexpr int NSUB   = CIN / 64;
  constexpr int KW     = CIN * 9;
  constexpr int NKMAIN = KW / 64;                 // 18 / 36
  constexpr int NKT    = (MODE == 2) ? NKMAIN + 2 : NKMAIN;

  __shared__ __align__(16) unsigned char lds[131072];
  const int tid  = threadIdx.x;
  const int wave = tid >> 6, lane = tid & 63;
  const int wm = wave >> 2, wn = wave & 3;        // 2 x 4 waves
  const int m_base = blockIdx.x * 256;
  const int bimg = m_base >> 12;
  const int ln = lane & 15, l4 = lane >> 4;

  // staging lane constants
  const int srow = lane >> 3;                     // 0..7
  const int glog = (lane & 7) ^ srow;             // pre-swizzled source granule

  u32 pixA[2][2], pixX[2][2], rowB[2][2], rowS[2][2];
#pragma unroll
  for (int j = 0; j < 2; ++j)
#pragma unroll
    for (int h = 0; h < 2; ++h) {
      int mlocal = (wave & 3) * 16 + j * 8 + srow + h * 64 + (wave >> 2) * 128;
      int m = m_base + mlocal;
      int y = (m >> 6) & 63, x = m & 63;
      pixA[j][h] = (u32)((bimg * HP + y) * WP + x) * CIN + glog * 8;
      if (MODE == 2) pixX[j][h] = (u32)m * 128 + glog * 8;
      int co = (wave >> 1) * 64 + h * 32 + (wave & 1) * 16 + j * 8 + srow;
      rowB[j][h] = (u32)co * KW + glog * 8;
      if (MODE == 2) rowS[j][h] = (u32)(bimg * 256 + co) * 128 + glog * 8;
    }

  f32x4 acc[8][4];
#pragma unroll
  for (int i = 0; i < 8; ++i)
#pragma unroll
    for (int j = 0; j < 4; ++j) acc[i][j] = (f32x4){0.f, 0.f, 0.f, 0.f};

  auto stageA = [&](int kt, int h, int buf) {
    unsigned char* dst = lds + buf * 65536 + h * 16384 + wave * 2048;
    if (MODE == 2 && kt >= NKMAIN) {
      u32 ko = (u32)(kt - NKMAIN) * 64;
      gload_lds16(xh + pixX[0][h] + ko, dst);
      gload_lds16(xh + pixX[1][h] + ko, dst + 1024);
    } else {
      int tap = kt / NSUB;
      int kin = (kt - tap * NSUB) * 64;
      int ky = tap / 3, kx = tap - ky * 3;
      u32 ko = (u32)((ky * WP + kx) * CIN + kin);
      gload_lds16(act + pixA[0][h] + ko, dst);
      gload_lds16(act + pixA[1][h] + ko, dst + 1024);
    }
  };
  auto stageB = [&](int kt, int g, int buf) {
    unsigned char* dst = lds + buf * 65536 + 32768 + g * 16384 + wave * 2048;
    if (MODE == 2 && kt >= NKMAIN) {
      u32 ko = (u32)(kt - NKMAIN) * 64;
      gload_lds16(scTb + rowS[0][g] + ko, dst);
      gload_lds16(scTb + rowS[1][g] + ko, dst + 1024);
    } else {
      u32 ko = (u32)kt * 64;
      gload_lds16(wT + rowB[0][g] + ko, dst);
      gload_lds16(wT + rowB[1][g] + ko, dst + 1024);
    }
  };

  bf16x8 af[8], bf[4];
  auto ldA = [&](int h, int buf) {
    const unsigned char* As = lds + buf * 65536;
#pragma unroll
    for (int f = 0; f < 4; ++f)
#pragma unroll
      for (int kk = 0; kk < 2; ++kk) {
        int lr = h * 128 + wm * 64 + f * 16 + ln;
        int gr = (kk * 4 + l4) ^ (ln & 7);
        af[f * 2 + kk] = *(const bf16x8*)(As + lr * 128 + gr * 16);
      }
  };
  auto ldB = [&](int g, int buf) {
    const unsigned char* Bs = lds + buf * 65536 + 32768;
#pragma unroll
    for (int f1 = 0; f1 < 2; ++f1)
#pragma unroll
      for (int kk = 0; kk < 2; ++kk) {
        int lr = g * 128 + wn * 32 + f1 * 16 + ln;
        int gr = (kk * 4 + l4) ^ (ln & 7);
        bf[f1 * 2 + kk] = *(const bf16x8*)(Bs + lr * 128 + gr * 16);
      }
  };
  auto mmac = [&](int h, int g) {
    __builtin_amdgcn_s_setprio(1);
#pragma unroll
    for (int f = 0; f < 4; ++f)
#pragma unroll
      for (int f1 = 0; f1 < 2; ++f1)
#pragma unroll
        for (int kk = 0; kk < 2; ++kk)
          acc[h * 4 + f][g * 2 + f1] = __builtin_amdgcn_mfma_f32_16x16x32_bf16(
              af[f * 2 + kk], bf[f1 * 2 + kk], acc[h * 4 + f][g * 2 + f1], 0, 0, 0);
    __builtin_amdgcn_s_setprio(0);
  };

#define PHASE_BAR() do { __builtin_amdgcn_sched_barrier(0); \
    __builtin_amdgcn_s_barrier(); __builtin_amdgcn_sched_barrier(0); } while (0)

  // prologue: tile 0 -> buf0, in consumption order Ah0, Bg0, Bg1, Ah1
  stageA(0, 0, 0); stageB(0, 0, 0); stageB(0, 1, 0); stageA(0, 1, 0);

#pragma unroll 2
  for (int kt = 0; kt < NKT - 1; ++kt) {
    const int cur = kt & 1, nxt = cur ^ 1;
    // ph0: (h0,g0)
    stageA(kt + 1, 0, nxt);
    asm volatile("s_waitcnt vmcnt(6)" ::: "memory");
    PHASE_BAR();
    ldB(0, cur); ldA(0, cur);
    mmac(0, 0);
    // ph1: (h0,g1)
    stageB(kt + 1, 0, nxt);
    asm volatile("s_waitcnt vmcnt(6)" ::: "memory");
    PHASE_BAR();
    ldB(1, cur);
    mmac(0, 1);
    // ph2: (h1,g1)
    stageB(kt + 1, 1, nxt);
    asm volatile("s_waitcnt vmcnt(6)" ::: "memory");
    PHASE_BAR();
    ldA(1, cur);
    mmac(1, 1);
    // ph3: (h1,g0)
    stageA(kt + 1, 1, nxt);
    PHASE_BAR();
    ldB(0, cur);
    mmac(1, 0);
  }
  {  // last tile (no staging): drain progressively
    const int cur = (NKT - 1) & 1;
    asm volatile("s_waitcnt vmcnt(4)" ::: "memory");
    PHASE_BAR();
    ldB(0, cur); ldA(0, cur); mmac(0, 0);
    asm volatile("s_waitcnt vmcnt(2)" ::: "memory");
    PHASE_BAR();
    ldB(1, cur); mmac(0, 1);
    asm volatile("s_waitcnt vmcnt(0)" ::: "memory");
    PHASE_BAR();
    ldA(1, cur); mmac(1, 1);
    PHASE_BAR();
    ldB(0, cur); mmac(1, 0);
  }
#undef PHASE_BAR

  if (MODE == 0) {
    const float* tbrow = epi + bimg * 256;
    float ps[4], ps2[4];
#pragma unroll
    for (int fn = 0; fn < 4; ++fn) { ps[fn] = 0.f; ps2[fn] = 0.f; }
#pragma unroll
    for (int fm = 0; fm < 8; ++fm)
#pragma unroll
      for (int fn = 0; fn < 4; ++fn) {
        int co = wn * 64 + fn * 16 + ln;
        float add = tbrow[co];
#pragma unroll
        for (int i = 0; i < 4; ++i) {
          int m = m_base + wm * 128 + fm * 16 + (l4 << 2) + i;
          float v = acc[fm][fn][i] + add;
          h1out[(size_t)m * 256 + co] = f2bf(v);
          ps[fn] += v; ps2[fn] += v * v;
        }
      }
    // fused GN2 partial stats: sum over the 8 channels of a group + all rows
#pragma unroll
    for (int fn = 0; fn < 4; ++fn) {
      float s = ps[fn], s2 = ps2[fn];
      s += __shfl_xor(s, 1);  s2 += __shfl_xor(s2, 1);
      s += __shfl_xor(s, 2);  s2 += __shfl_xor(s2, 2);
      s += __shfl_xor(s, 4);  s2 += __shfl_xor(s2, 4);
      s += __shfl_xor(s, 16); s2 += __shfl_xor(s2, 16);
      s += __shfl_xor(s, 32); s2 += __shfl_xor(s2, 32);
      if ((lane & 55) == 0) {                 // lanes 0 and 8
        int g = wn * 8 + fn * 2 + (ln >> 3);
        atomicAdd(&st2sum[bimg * 64 + g * 2 + 0], s);
        atomicAdd(&st2sum[bimg * 64 + g * 2 + 1], s2);
      }
    }
  } else {
    float* tile = (float*)lds;              // [64][257] f32
    const int pixb = m_base & 4095;
#pragma unroll
    for (int c = 0; c < 4; ++c) {
      __syncthreads();
      if (wn == c) {
#pragma unroll
        for (int fn = 0; fn < 4; ++fn) {
          int nl = fn * 16 + ln;
          int co = c * 64 + nl;
          float dsc = epi[bimg * 256 + co];
          float scb = sc_b[co];
#pragma unroll
          for (int fm = 0; fm < 8; ++fm)
#pragma unroll
            for (int i = 0; i < 4; ++i) {
              int ml = wm * 128 + fm * 16 + (l4 << 2) + i;
              tile[nl * 257 + ml] = acc[fm][fn][i] * dsc + scb;
            }
        }
      }
      __syncthreads();
#pragma unroll 4
      for (int it = 0; it < 32; ++it) {
        int lin = it * 512 + tid;
        int co_l = lin >> 8, ml = lin & 255;
        fout[((size_t)(bimg * 256 + c * 64 + co_l)) * 4096 + pixb + ml] =
            tile[co_l * 257 + ml];
      }
    }
  }
}

// ------------------------------- launch -------------------------------
extern "C" void kernel_launch(void* const* d_in, const int* in_sizes, int n_in,
                              void* d_out, int out_size, void* d_ws, size_t ws_size,
                              hipStream_t stream) {
  const float* x       = (const float*)d_in[0];
  const float* temb    = (const float*)d_in[1];
  const float* style   = (const float*)d_in[2];
  const float* gn1_g   = (const float*)d_in[3];
  const float* gn1_b   = (const float*)d_in[4];
  const float* conv1_w = (const float*)d_in[5];
  const float* conv1_b = (const float*)d_in[6];
  const float* temb_w  = (const float*)d_in[7];
  const float* temb_b  = (const float*)d_in[8];
  const float* gn2_g   = (const float*)d_in[9];
  const float* gn2_b   = (const float*)d_in[10];
  const float* style_w = (const float*)d_in[11];
  const float* style_b = (const float*)d_in[12];
  const float* mod_w   = (const float*)d_in[13];
  const float* sc_w    = (const float*)d_in[14];
  const float* sc_b    = (const float*)d_in[15];
  float* out = (float*)d_out;
  char* ws = (char*)d_ws;

  size_t o = 0;
  auto alloc = [&](size_t bytes) { size_t r = o; o += (bytes + 255) & ~(size_t)255; return r; };
  const size_t act1p_bytes = (size_t)32 * HP * WP * 128 * 2;
  const size_t xh_bytes    = (size_t)32 * 64 * 64 * 128 * 2;
  const size_t h1_bytes    = (size_t)32 * 4096 * 256 * 2;
  const size_t act2p_bytes = (size_t)32 * HP * WP * 256 * 2;
  size_t o_act1p = alloc(act1p_bytes);
  size_t o_xh    = alloc(xh_bytes);
  size_t o_h1    = alloc(h1_bytes);
  size_t o_act2p = alloc(act2p_bytes);
  size_t o_w1T   = alloc((size_t)256 * 1152 * 2);
  size_t o_wmT   = alloc((size_t)256 * 2304 * 2);
  size_t o_scTb  = alloc((size_t)32 * 256 * 128 * 2);
  size_t o_tb2   = alloc(8192 * 4);
  size_t o_mvec  = alloc(8192 * 4);
  size_t o_dvec  = alloc(8192 * 4);
  size_t o_SS    = alloc((size_t)256 * 256 * 4);
  size_t o_st1   = alloc(1024 * 8);
  size_t o_st2   = alloc(1024 * 8);
  size_t o_s2sum = alloc(32 * 32 * 2 * 4);
  if (ws_size < o) return;

  u16*    act1p = (u16*)(ws + o_act1p);
  u16*    xh    = (u16*)(ws + o_xh);
  u16*    h1    = (u16*)(ws + o_h1);
  u16*    act2p = (u16*)(ws + o_act2p);
  u16*    w1T   = (u16*)(ws + o_w1T);
  u16*    wmT   = (u16*)(ws + o_wmT);
  u16*    scTb  = (u16*)(ws + o_scTb);
  float*  tb2   = (float*)(ws + o_tb2);
  float*  mvec  = (float*)(ws + o_mvec);
  float*  dvec  = (float*)(ws + o_dvec);
  float*  SS_T  = (float*)(ws + o_SS);
  float2* st1   = (float2*)(ws + o_st1);
  float2* st2   = (float2*)(ws + o_st2);
  float*  s2sum = (float*)(ws + o_s2sum);

  // zero halo borders + GN2 atomic accumulator
  halo_zero_kernel<128><<<(32 * 260 * 16 + 255) / 256, 256, 0, stream>>>(act1p);
  halo_zero_kernel<256><<<(32 * 260 * 32 + 255) / 256, 256, 0, stream>>>(act2p);
  hipMemsetAsync(s2sum, 0, 32 * 32 * 2 * 4, stream);

  repack_w_kernel<<<1152, 256, 0, stream>>>(conv1_w, w1T, 128, 1152, 256 * 1152, 9, 3);
  repack_w_kernel<<<2304, 256, 0, stream>>>(mod_w, wmT, 256, 2304, 256 * 2304, 9, 3);
  modw_ss_kernel<<<256, 256, 0, stream>>>(mod_w, SS_T);
  temb_proj_kernel<<<32, 256, 0, stream>>>(temb, temb_w, temb_b, conv1_b, tb2);
  style_mvec_kernel<<<32, 256, 0, stream>>>(style, style_w, style_b, mvec);
  demod_kernel<<<32, 256, 0, stream>>>(mvec, SS_T, dvec);
  scale_sc_kernel<<<4096, 256, 0, stream>>>(sc_w, dvec, scTb);
  gn1_stats_kernel<<<1024, 256, 0, stream>>>(x, st1);
  gn1_apply_kernel<<<2048, 256, 0, stream>>>(x, st1, gn1_g, gn1_b, act1p, xh);

  igemm_kernel<0><<<512, 512, 0, stream>>>(act1p, w1T, tb2, nullptr, nullptr,
                                           nullptr, h1, nullptr, s2sum);

  gn2_final_kernel<<<4, 256, 0, stream>>>(s2sum, st2);
  gn2_apply_kernel<<<16384, 256, 0, stream>>>(h1, st2, gn2_g, gn2_b, mvec, act2p);

  igemm_kernel<2><<<512, 512, 0, stream>>>(act2p, wmT, dvec, xh, scTb,
                                           sc_b, nullptr, out, nullptr);
}